// Round 3
// baseline (203.327 us; speedup 1.0000x reference)
//
#include <hip/hip_runtime.h>
#include <math.h>

#define IMG_H 512
#define IMG_W 512
#define NIMG 32
#define R_ROWS 4        // rows per block in pass 1
#define RB_W 552        // rowbuf padded width; cmax x -> index 20+x, halo [0..19] & [532..551]
#define T5_W 544        // tmp5 padded width (542 used, 2 tail slots are -inf, never read)
#define YC2 32          // output rows per block in pass 2

// ---------------- Pass 1: cmax + horizontal win35 (win5 then 7-tap stride-5) ----------
__global__ __launch_bounds__(256) void dc_rowmax(const float* __restrict__ img,
                                                 float* __restrict__ rowmax) {
    __shared__ float rowbuf[R_ROWS][RB_W];
    __shared__ float tmp5[R_ROWS][T5_W];
    const int b = blockIdx.x;            // n*128 + ytile
    const int n = b >> 7;
    const int y0 = (b & 127) * R_ROWS;
    const int tid = threadIdx.x;

    // halo fill: indices [0,20) and [532,552) per row = 40 each
    for (int i = tid; i < R_ROWS * 40; i += 256) {
        int r = i / 40, j = i - r * 40;
        int idx = (j < 20) ? j : (512 + j);  // j<20 -> [0,20); else 532..551
        rowbuf[r][idx] = -INFINITY;
    }
    // main fill: 512 float4 positions (4 rows x 128), cmax = 1 - min over 3 channels
    const float4* imgb = (const float4*)(img + ((size_t)n * 3 * IMG_H + y0) * IMG_W);
    for (int p = tid; p < R_ROWS * 128; p += 256) {
        int r = p >> 7, xq = p & 127;
        int o = r * 128 + xq;
        float4 a = imgb[o];
        float4 b4 = imgb[65536 + o];     // + H*W/4
        float4 c4 = imgb[131072 + o];    // + 2*H*W/4
        float4 m;
        m.x = 1.0f - fminf(a.x, fminf(b4.x, c4.x));
        m.y = 1.0f - fminf(a.y, fminf(b4.y, c4.y));
        m.z = 1.0f - fminf(a.z, fminf(b4.z, c4.z));
        m.w = 1.0f - fminf(a.w, fminf(b4.w, c4.w));
        *(float4*)&rowbuf[r][20 + 4 * xq] = m;   // (20+4xq)*4B is 16B-aligned
    }
    __syncthreads();
    // win5, 4 outputs per task: tmp5[4q+d] = max(rowbuf[4q+3+d .. 4q+7+d]), d=0..3
    for (int p = tid; p < R_ROWS * 136; p += 256) {
        int r = p / 136, q = p - r * 136;
        const float4* rb = (const float4*)&rowbuf[r][0];   // row base 16B-aligned (552*4B)
        float4 w0 = rb[q], w1 = rb[q + 1], w2 = rb[q + 2];
        float f3 = w0.w, f4 = w1.x, f5 = w1.y, f6 = w1.z, f7 = w1.w;
        float f8 = w2.x, f9 = w2.y, f10 = w2.z;
        float a34 = fmaxf(f3, f4), a45 = fmaxf(f4, f5), a56 = fmaxf(f5, f6);
        float a67 = fmaxf(f6, f7), a78 = fmaxf(f7, f8), a89 = fmaxf(f8, f9);
        float4 o;
        o.x = fmaxf(fmaxf(a34, a56), f7);
        o.y = fmaxf(fmaxf(a45, a67), f8);
        o.z = fmaxf(fmaxf(a56, a78), f9);
        o.w = fmaxf(fmaxf(a67, a89), f10);
        *(float4*)&tmp5[r][4 * q] = o;           // T5_W*4B row stride is 16B-aligned
    }
    __syncthreads();
    // win35, 4 outputs per task: out[4q+d] = max_k tmp5[4q+d+5k], k=0..6
    float* orow = rowmax + ((size_t)n * IMG_H + y0) * IMG_W;
    for (int p = tid; p < R_ROWS * 128; p += 256) {
        int r = p >> 7, q = p & 127;
        const float4* t5 = (const float4*)&tmp5[r][0];
        float wf[36];                            // static-indexed after unroll -> registers
        #pragma unroll
        for (int k = 0; k < 9; ++k) {
            float4 t = t5[q + k];
            wf[4 * k + 0] = t.x; wf[4 * k + 1] = t.y;
            wf[4 * k + 2] = t.z; wf[4 * k + 3] = t.w;
        }
        float4 o;
        #define M7(d) fmaxf(fmaxf(fmaxf(wf[(d)], wf[(d) + 5]), fmaxf(wf[(d) + 10], wf[(d) + 15])), \
                            fmaxf(fmaxf(wf[(d) + 20], wf[(d) + 25]), wf[(d) + 30]))
        o.x = M7(0); o.y = M7(1); o.z = M7(2); o.w = M7(3);
        #undef M7
        *(float4*)&orow[(size_t)r * IMG_W + 4 * q] = o;
    }
}

// -------- Pass 2: vertical win35 = win5 (shift ring) o win7-stride-5 (phase rings) ----
__global__ __launch_bounds__(256) void dc_colmax(const float* __restrict__ rowmax,
                                                 float* __restrict__ out) {
    __shared__ float wsum[4];
    const int b = blockIdx.x;            // n*16 + yt
    const int yt = b & 15;
    const int n = b >> 4;
    const int x0 = (int)threadIdx.x * 2; // columns x0, x0+1
    const int y0 = yt * YC2;
    const float2* col = (const float2*)(rowmax + (size_t)n * (IMG_H * IMG_W) + x0);

    float G0[5][6], G1[5][6];            // all accesses use literal [P][slot]
    #pragma unroll
    for (int p = 0; p < 5; ++p)
        #pragma unroll
        for (int k = 0; k < 6; ++k) { G0[p][k] = -INFINITY; G1[p][k] = -INFINITY; }

    float a1, a2, a3, a4;                // win5 shift ring, column x0
    float b1, b2, b3, b4;                // win5 shift ring, column x0+1
    float s = 0.0f;

    // prologue: rows gy = y0-17 .. y0-14
    {
        const int gy = y0 - 17;
        float2 v0 = ((unsigned)(gy + 0) < IMG_H) ? col[(size_t)(gy + 0) * (IMG_W / 2)]
                                                 : make_float2(-INFINITY, -INFINITY);
        float2 v1 = ((unsigned)(gy + 1) < IMG_H) ? col[(size_t)(gy + 1) * (IMG_W / 2)]
                                                 : make_float2(-INFINITY, -INFINITY);
        float2 v2 = ((unsigned)(gy + 2) < IMG_H) ? col[(size_t)(gy + 2) * (IMG_W / 2)]
                                                 : make_float2(-INFINITY, -INFINITY);
        float2 v3 = ((unsigned)(gy + 3) < IMG_H) ? col[(size_t)(gy + 3) * (IMG_W / 2)]
                                                 : make_float2(-INFINITY, -INFINITY);
        a1 = v0.x; a2 = v1.x; a3 = v2.x; a4 = v3.x;
        b1 = v0.y; b2 = v1.y; b3 = v2.y; b4 = v3.y;
    }

#define PUSH(P, J, DO_OUT)                                                              \
    {                                                                                   \
        const int gy_ = y0 - 13 + (J);                                                  \
        float2 v_ = ((unsigned)gy_ < IMG_H) ? col[(size_t)gy_ * (IMG_W / 2)]            \
                                            : make_float2(-INFINITY, -INFINITY);        \
        float gA_ = fmaxf(fmaxf(fmaxf(a1, a2), fmaxf(a3, a4)), v_.x);                   \
        float gB_ = fmaxf(fmaxf(fmaxf(b1, b2), fmaxf(b3, b4)), v_.y);                   \
        a1 = a2; a2 = a3; a3 = a4; a4 = v_.x;                                           \
        b1 = b2; b2 = b3; b3 = b4; b4 = v_.y;                                           \
        if (DO_OUT) {                                                                   \
            float oA_ = fmaxf(fmaxf(fmaxf(G0[P][0], G0[P][1]), fmaxf(G0[P][2], G0[P][3])), \
                              fmaxf(fmaxf(G0[P][4], G0[P][5]), gA_));                   \
            float oB_ = fmaxf(fmaxf(fmaxf(G1[P][0], G1[P][1]), fmaxf(G1[P][2], G1[P][3])), \
                              fmaxf(fmaxf(G1[P][4], G1[P][5]), gB_));                   \
            s += fabsf(oA_) + fabsf(oB_);                                               \
        }                                                                               \
        G0[P][0] = G0[P][1]; G0[P][1] = G0[P][2]; G0[P][2] = G0[P][3];                  \
        G0[P][3] = G0[P][4]; G0[P][4] = G0[P][5]; G0[P][5] = gA_;                       \
        G1[P][0] = G1[P][1]; G1[P][1] = G1[P][2]; G1[P][2] = G1[P][3];                  \
        G1[P][3] = G1[P][4]; G1[P][4] = G1[P][5]; G1[P][5] = gB_;                       \
    }

    // warm-up: J = 0..29, no outputs yet
    #pragma unroll
    for (int g5 = 0; g5 < 6; ++g5) {
        const int j0 = 5 * g5;
        PUSH(0, j0 + 0, 0) PUSH(1, j0 + 1, 0) PUSH(2, j0 + 2, 0)
        PUSH(3, j0 + 3, 0) PUSH(4, j0 + 4, 0)
    }
    // steady: J = 30..59 -> outputs y = 0..29
    #pragma unroll
    for (int g5 = 6; g5 < 12; ++g5) {
        const int j0 = 5 * g5;
        PUSH(0, j0 + 0, 1) PUSH(1, j0 + 1, 1) PUSH(2, j0 + 2, 1)
        PUSH(3, j0 + 3, 1) PUSH(4, j0 + 4, 1)
    }
    // tail: J = 60, 61 -> outputs y = 30, 31
    PUSH(0, 60, 1)
    PUSH(1, 61, 1)
#undef PUSH

    // wave64 reduce then cross-wave
    #pragma unroll
    for (int off = 32; off > 0; off >>= 1) s += __shfl_down(s, off);
    const int lane = (int)threadIdx.x & 63, wv = (int)threadIdx.x >> 6;
    if (lane == 0) wsum[wv] = s;
    __syncthreads();
    if (threadIdx.x == 0) {
        float t = wsum[0] + wsum[1] + wsum[2] + wsum[3];
        atomicAdd(out, t * (1.0f / ((float)NIMG * IMG_H * IMG_W)));
    }
}

extern "C" void kernel_launch(void* const* d_in, const int* in_sizes, int n_in,
                              void* d_out, int out_size, void* d_ws, size_t ws_size,
                              hipStream_t stream) {
    const float* img = (const float*)d_in[0];
    float* out = (float*)d_out;
    float* rowmax = (float*)d_ws;    // 32*512*512 floats = 33.5 MB scratch

    // ===== ATTRIBUTION ROUND =====
    // Each kernel launched twice; output re-zeroed before the final colmax so the
    // result is bit-identical to the single-launch version (p1 idempotent, last p2
    // fully defines out). dur_us(this) - dur_us(R2=163.09) = p1 + p2.
    dc_rowmax<<<NIMG * (IMG_H / R_ROWS), 256, 0, stream>>>(img, rowmax);   // probe +p1
    dc_rowmax<<<NIMG * (IMG_H / R_ROWS), 256, 0, stream>>>(img, rowmax);   // real
    hipMemsetAsync(d_out, 0, sizeof(float), stream);
    dc_colmax<<<NIMG * 16, 256, 0, stream>>>(rowmax, out);                 // probe +p2
    hipMemsetAsync(d_out, 0, sizeof(float), stream);
    dc_colmax<<<NIMG * 16, 256, 0, stream>>>(rowmax, out);                 // real (authoritative)
}

// Round 4
// 161.062 us; speedup vs baseline: 1.2624x; 1.2624x over previous
//
#include <hip/hip_runtime.h>
#include <math.h>

#define IMG_H 512
#define IMG_W 512
#define NIMG 32
#define R_ROWS 4        // rows per block in pass 1 (one row per wave, 4 waves)
#define RB_W 552        // rowbuf padded width; cmax x -> index 20+x, halo [0..19] & [532..551]
#define T5_W 544        // tmp5 padded width (542 used, 2 tail slots never read)
#define YC2 32          // output rows per block in pass 2

// ---------------- Pass 1: cmax + horizontal win35, BARRIER-FREE (wave-per-row) --------
// Each wave owns one image row end-to-end: fill -> win5 -> win35. Cross-lane LDS data
// flow is within-wave only, so __syncthreads() is replaced by per-wave
// s_waitcnt lgkmcnt(0) (asm, "memory" clobber) — no s_barrier, no collective vmcnt(0)
// drain; the 32 waves/CU become independent row-pipelines.
__global__ __launch_bounds__(256) void dc_rowmax(const float* __restrict__ img,
                                                 float* __restrict__ rowmax) {
    __shared__ float rowbuf[R_ROWS][RB_W];
    __shared__ float tmp5[R_ROWS][T5_W];
    const int b = blockIdx.x;            // n*128 + ytile
    const int n = b >> 7;
    const int y0 = (b & 127) * R_ROWS;
    const int tid = (int)threadIdx.x;
    const int lane = tid & 63;
    const int wv = tid >> 6;             // wave -> row
    const int y = y0 + wv;

    // halo: lanes 0..39 write the 40 pad cells of this wave's row
    if (lane < 40) {
        int idx = (lane < 20) ? lane : (512 + lane);   // [0,20) and [532,552)
        rowbuf[wv][idx] = -INFINITY;
    }
    // fill: 128 float4 positions per row over 64 lanes (2 each)
    const float4* imgr = (const float4*)(img + ((size_t)n * 3 * IMG_H + y) * IMG_W);
    #pragma unroll
    for (int i = 0; i < 2; ++i) {
        int xq = lane + 64 * i;
        float4 a = imgr[xq];
        float4 b4 = imgr[65536 + xq];    // + H*W/4 (next channel)
        float4 c4 = imgr[131072 + xq];   // + 2*H*W/4
        float4 m;
        m.x = 1.0f - fminf(a.x, fminf(b4.x, c4.x));
        m.y = 1.0f - fminf(a.y, fminf(b4.y, c4.y));
        m.z = 1.0f - fminf(a.z, fminf(b4.z, c4.z));
        m.w = 1.0f - fminf(a.w, fminf(b4.w, c4.w));
        *(float4*)&rowbuf[wv][20 + 4 * xq] = m;       // 16B-aligned
    }
    // within-wave LDS visibility: all this wave's ds_writes retired before any ds_read
    asm volatile("s_waitcnt lgkmcnt(0)" ::: "memory");
    __builtin_amdgcn_sched_barrier(0);

    // win5: tmp5[4q+d] = max(rowbuf[4q+3+d .. 4q+7+d]); 136 quad-tasks per row
    const float4* rb = (const float4*)&rowbuf[wv][0];  // row base 16B-aligned (552*4B)
    #pragma unroll
    for (int i = 0; i < 3; ++i) {
        int q = lane + 64 * i;
        if (i < 2 || lane < 8) {                       // 64+64+8 = 136
            float4 w0 = rb[q], w1 = rb[q + 1], w2 = rb[q + 2];
            float f3 = w0.w, f4 = w1.x, f5 = w1.y, f6 = w1.z, f7 = w1.w;
            float f8 = w2.x, f9 = w2.y, f10 = w2.z;
            float a34 = fmaxf(f3, f4), a45 = fmaxf(f4, f5), a56 = fmaxf(f5, f6);
            float a67 = fmaxf(f6, f7), a78 = fmaxf(f7, f8), a89 = fmaxf(f8, f9);
            float4 o;
            o.x = fmaxf(fmaxf(a34, a56), f7);
            o.y = fmaxf(fmaxf(a45, a67), f8);
            o.z = fmaxf(fmaxf(a56, a78), f9);
            o.w = fmaxf(fmaxf(a67, a89), f10);
            *(float4*)&tmp5[wv][4 * q] = o;            // 16B-aligned (544*4B row stride)
        }
    }
    asm volatile("s_waitcnt lgkmcnt(0)" ::: "memory");
    __builtin_amdgcn_sched_barrier(0);

    // win35: out[4q+d] = max_k tmp5[4q+d+5k], k=0..6; 128 quad-tasks per row
    float* orow = rowmax + ((size_t)n * IMG_H + y) * IMG_W;
    const float4* t5 = (const float4*)&tmp5[wv][0];
    #pragma unroll
    for (int i = 0; i < 2; ++i) {
        int q = lane + 64 * i;
        float wf[36];                                  // static-indexed -> registers
        #pragma unroll
        for (int k = 0; k < 9; ++k) {
            float4 t = t5[q + k];
            wf[4 * k + 0] = t.x; wf[4 * k + 1] = t.y;
            wf[4 * k + 2] = t.z; wf[4 * k + 3] = t.w;
        }
        float4 o;
        #define M7(d) fmaxf(fmaxf(fmaxf(wf[(d)], wf[(d) + 5]), fmaxf(wf[(d) + 10], wf[(d) + 15])), \
                            fmaxf(fmaxf(wf[(d) + 20], wf[(d) + 25]), wf[(d) + 30]))
        o.x = M7(0); o.y = M7(1); o.z = M7(2); o.w = M7(3);
        #undef M7
        *(float4*)&orow[4 * q] = o;
    }
}

// -------- Pass 2: vertical win35 = win5 (shift ring) o win7-stride-5 (phase rings) ----
// Unchanged from R2: float2 per thread, literal-indexed register rings, 512 blocks.
__global__ __launch_bounds__(256) void dc_colmax(const float* __restrict__ rowmax,
                                                 float* __restrict__ out) {
    __shared__ float wsum[4];
    const int b = blockIdx.x;            // n*16 + yt
    const int yt = b & 15;
    const int n = b >> 4;
    const int x0 = (int)threadIdx.x * 2; // columns x0, x0+1
    const int y0 = yt * YC2;
    const float2* col = (const float2*)(rowmax + (size_t)n * (IMG_H * IMG_W) + x0);

    float G0[5][6], G1[5][6];            // all accesses use literal [P][slot]
    #pragma unroll
    for (int p = 0; p < 5; ++p)
        #pragma unroll
        for (int k = 0; k < 6; ++k) { G0[p][k] = -INFINITY; G1[p][k] = -INFINITY; }

    float a1, a2, a3, a4;                // win5 shift ring, column x0
    float b1, b2, b3, b4;                // win5 shift ring, column x0+1
    float s = 0.0f;

    // prologue: rows gy = y0-17 .. y0-14
    {
        const int gy = y0 - 17;
        float2 v0 = ((unsigned)(gy + 0) < IMG_H) ? col[(size_t)(gy + 0) * (IMG_W / 2)]
                                                 : make_float2(-INFINITY, -INFINITY);
        float2 v1 = ((unsigned)(gy + 1) < IMG_H) ? col[(size_t)(gy + 1) * (IMG_W / 2)]
                                                 : make_float2(-INFINITY, -INFINITY);
        float2 v2 = ((unsigned)(gy + 2) < IMG_H) ? col[(size_t)(gy + 2) * (IMG_W / 2)]
                                                 : make_float2(-INFINITY, -INFINITY);
        float2 v3 = ((unsigned)(gy + 3) < IMG_H) ? col[(size_t)(gy + 3) * (IMG_W / 2)]
                                                 : make_float2(-INFINITY, -INFINITY);
        a1 = v0.x; a2 = v1.x; a3 = v2.x; a4 = v3.x;
        b1 = v0.y; b2 = v1.y; b3 = v2.y; b4 = v3.y;
    }

#define PUSH(P, J, DO_OUT)                                                              \
    {                                                                                   \
        const int gy_ = y0 - 13 + (J);                                                  \
        float2 v_ = ((unsigned)gy_ < IMG_H) ? col[(size_t)gy_ * (IMG_W / 2)]            \
                                            : make_float2(-INFINITY, -INFINITY);        \
        float gA_ = fmaxf(fmaxf(fmaxf(a1, a2), fmaxf(a3, a4)), v_.x);                   \
        float gB_ = fmaxf(fmaxf(fmaxf(b1, b2), fmaxf(b3, b4)), v_.y);                   \
        a1 = a2; a2 = a3; a3 = a4; a4 = v_.x;                                           \
        b1 = b2; b2 = b3; b3 = b4; b4 = v_.y;                                           \
        if (DO_OUT) {                                                                   \
            float oA_ = fmaxf(fmaxf(fmaxf(G0[P][0], G0[P][1]), fmaxf(G0[P][2], G0[P][3])), \
                              fmaxf(fmaxf(G0[P][4], G0[P][5]), gA_));                   \
            float oB_ = fmaxf(fmaxf(fmaxf(G1[P][0], G1[P][1]), fmaxf(G1[P][2], G1[P][3])), \
                              fmaxf(fmaxf(G1[P][4], G1[P][5]), gB_));                   \
            s += fabsf(oA_) + fabsf(oB_);                                               \
        }                                                                               \
        G0[P][0] = G0[P][1]; G0[P][1] = G0[P][2]; G0[P][2] = G0[P][3];                  \
        G0[P][3] = G0[P][4]; G0[P][4] = G0[P][5]; G0[P][5] = gA_;                       \
        G1[P][0] = G1[P][1]; G1[P][1] = G1[P][2]; G1[P][2] = G1[P][3];                  \
        G1[P][3] = G1[P][4]; G1[P][4] = G1[P][5]; G1[P][5] = gB_;                       \
    }

    // warm-up: J = 0..29, no outputs yet
    #pragma unroll
    for (int g5 = 0; g5 < 6; ++g5) {
        const int j0 = 5 * g5;
        PUSH(0, j0 + 0, 0) PUSH(1, j0 + 1, 0) PUSH(2, j0 + 2, 0)
        PUSH(3, j0 + 3, 0) PUSH(4, j0 + 4, 0)
    }
    // steady: J = 30..59 -> outputs y = 0..29
    #pragma unroll
    for (int g5 = 6; g5 < 12; ++g5) {
        const int j0 = 5 * g5;
        PUSH(0, j0 + 0, 1) PUSH(1, j0 + 1, 1) PUSH(2, j0 + 2, 1)
        PUSH(3, j0 + 3, 1) PUSH(4, j0 + 4, 1)
    }
    // tail: J = 60, 61 -> outputs y = 30, 31
    PUSH(0, 60, 1)
    PUSH(1, 61, 1)
#undef PUSH

    // wave64 reduce then cross-wave
    #pragma unroll
    for (int off = 32; off > 0; off >>= 1) s += __shfl_down(s, off);
    const int lane = (int)threadIdx.x & 63, wv = (int)threadIdx.x >> 6;
    if (lane == 0) wsum[wv] = s;
    __syncthreads();
    if (threadIdx.x == 0) {
        float t = wsum[0] + wsum[1] + wsum[2] + wsum[3];
        atomicAdd(out, t * (1.0f / ((float)NIMG * IMG_H * IMG_W)));
    }
}

extern "C" void kernel_launch(void* const* d_in, const int* in_sizes, int n_in,
                              void* d_out, int out_size, void* d_ws, size_t ws_size,
                              hipStream_t stream) {
    const float* img = (const float*)d_in[0];
    float* out = (float*)d_out;
    float* rowmax = (float*)d_ws;    // 32*512*512 floats = 33.5 MB scratch

    hipMemsetAsync(d_out, 0, sizeof(float), stream);
    dc_rowmax<<<NIMG * (IMG_H / R_ROWS), 256, 0, stream>>>(img, rowmax);
    dc_colmax<<<NIMG * 16, 256, 0, stream>>>(rowmax, out);
}